// Round 7
// baseline (593.425 us; speedup 1.0000x reference)
//
#include <hip/hip_runtime.h>
#include <hip/hip_bf16.h>
#include <cstdint>

#define N_NODES 118784
#define N_EDGES 1900544
#define NROI 116
#define HID 64
#define D1 3712
#define BATCH 1024
#define KDIM 7424   // N_ROI * HIDDEN

// sort geometry: 232 blocks x 8192 edges == N_EDGES ; 464 buckets x 256 nodes == N_NODES
#define EPB 8192
#define NBLK 232
#define BUCKETS 464

typedef __attribute__((ext_vector_type(8))) short s16x8;
typedef __attribute__((ext_vector_type(4))) float f32x4;

__device__ __forceinline__ float mishf(float x) {
    if (x > 20.f) return x;
    float e = __expf(x);
    float n = e * e + 2.f * e;
    return x * n / (n + 2.f);
}
__device__ __forceinline__ float bflo(unsigned u) { return __uint_as_float(u << 16); }
__device__ __forceinline__ float bfhi(unsigned u) { return __uint_as_float(u & 0xFFFF0000u); }

// async global->LDS DMA, 16B per lane. LDS dest = wave-uniform base + lane*16.
__device__ __forceinline__ void gload16(const void* g, void* l) {
    __builtin_amdgcn_global_load_lds(
        (const __attribute__((address_space(1))) void*)g,
        (__attribute__((address_space(3))) void*)l, 16, 0, 0);
}

// --- fused prep: BT1/bias1p (blocks 0..127), BT2 (128..191), xb (192..) ------
// xb rows padded 116 -> 128 bf16 (256B): aligned 64B lines for gather1, pad=0.
__global__ __launch_bounds__(256) void prep_kernel(
    const float* __restrict__ w1_l, const float* __restrict__ w1_r,
    const float* __restrict__ b1,
    const float* __restrict__ w2_l, const float* __restrict__ w2_r,
    const float* __restrict__ x,
    __hip_bfloat16* __restrict__ BT1, float* __restrict__ bias1p,
    __hip_bfloat16* __restrict__ BT2, __hip_bfloat16* __restrict__ xb) {
    int bid = blockIdx.x, t = threadIdx.x;
    if (bid < 128) {            // BT1 [128][256] = padded [w1_l; w1_r]^T
        int idx = bid * 256 + t;
        int j = idx >> 8, k = idx & 255;
        float v = 0.f;
        if (j < NROI) {
            if (k < NROI) v = w1_l[k * NROI + j];
            else if (k < 2 * NROI) v = w1_r[(k - NROI) * NROI + j];
        }
        BT1[idx] = __float2bfloat16(v);
        if (idx < 128) bias1p[idx] = (idx < NROI) ? b1[idx] : 0.f;
    } else if (bid < 192) {     // BT2 [128][128] = padded [w2_l | w2_r]^T
        int idx = (bid - 128) * 256 + t;
        int j = idx >> 7, k = idx & 127;
        float v = 0.f;
        if (k < NROI) v = (j < HID) ? w2_l[k * HID + j] : w2_r[k * HID + (j - HID)];
        BT2[idx] = __float2bfloat16(v);
    } else {                    // xb: x fp32 -> bf16, padded [N][128] rows
        long i = (long)(bid - 192) * 256 + t;     // pair idx; grid gives i < N*64
        int node = (int)(i >> 6);
        int p = (int)(i & 63);                    // pair p covers cols 2p,2p+1
        __hip_bfloat162 o;
        if (p < 58) {
            float2 v = *(const float2*)(x + (long)node * NROI + 2 * p);
            o.x = __float2bfloat16(v.x);
            o.y = __float2bfloat16(v.y);
        } else {
            o.x = __float2bfloat16(0.f);
            o.y = __float2bfloat16(0.f);
        }
        *(__hip_bfloat162*)((__hip_bfloat16*)xb + 2 * i) = o;
    }
}

// =============== deterministic CSR build via 2-level counting sort ===========
__global__ __launch_bounds__(256) void sortA_kernel(const int* __restrict__ dst,
                                                    int* __restrict__ HT) {
    __shared__ int h[BUCKETS];
    int t = threadIdx.x;
    for (int i = t; i < BUCKETS; i += 256) h[i] = 0;
    __syncthreads();
    int base = blockIdx.x * EPB;
    for (int i = t; i < EPB; i += 256) atomicAdd(&h[dst[base + i] >> 8], 1);
    __syncthreads();
    for (int i = t; i < BUCKETS; i += 256) HT[i * NBLK + blockIdx.x] = h[i];
}

// prefix sum of 107648 ints, single block, wave-shuffle scan (4 barriers/chunk
// instead of 22 -- the old Hillis-Steele version was ~30us of serial barriers).
__global__ __launch_bounds__(1024) void sortB_kernel(int* __restrict__ HT) {
    const int L = BUCKETS * NBLK;   // 107648
    __shared__ int wsum[16];
    __shared__ int carry_s;
    int t = threadIdx.x;
    int lane = t & 63, wv = t >> 6;
    if (t == 0) carry_s = 0;
    __syncthreads();
    for (int base = 0; base < L; base += 4096) {
        int i0 = base + 4 * t;
        int4 v = {0, 0, 0, 0};
        if (i0 + 3 < L) v = *(const int4*)(HT + i0);
        else {
            if (i0 < L) v.x = HT[i0];
            if (i0 + 1 < L) v.y = HT[i0 + 1];
            if (i0 + 2 < L) v.z = HT[i0 + 2];
        }
        int s4 = v.x + v.y + v.z + v.w;
        // wave-level inclusive scan of s4 (no barriers)
        int sc = s4;
#pragma unroll
        for (int d = 1; d < 64; d <<= 1) {
            int a = __shfl_up(sc, d);
            if (lane >= d) sc += a;
        }
        if (lane == 63) wsum[wv] = sc;
        __syncthreads();
        if (wv == 0 && lane < 16) {   // scan the 16 wave totals
            int xv = wsum[lane];
#pragma unroll
            for (int d = 1; d < 16; d <<= 1) {
                int a = __shfl_up(xv, d);
                if (lane >= d) xv += a;
            }
            wsum[lane] = xv;          // inclusive
        }
        __syncthreads();
        int wbase = (wv == 0) ? 0 : wsum[wv - 1];
        int carry = carry_s;
        int excl = carry + wbase + sc - s4;
        int4 o;
        o.x = excl; o.y = excl + v.x; o.z = o.y + v.y; o.w = o.z + v.z;
        if (i0 + 3 < L) *(int4*)(HT + i0) = o;
        else {
            if (i0 < L) HT[i0] = o.x;
            if (i0 + 1 < L) HT[i0 + 1] = o.y;
            if (i0 + 2 < L) HT[i0 + 2] = o.z;
        }
        __syncthreads();              // all reads of carry_s/wsum done
        if (t == 1023) carry_s = carry + wsum[15];
        __syncthreads();
    }
}

// C: scatter packed (src | dlow<<24) into bucket-sorted order (4B vs 8B pairs)
__global__ __launch_bounds__(256) void sortC_kernel(const int* __restrict__ src,
                                                    const int* __restrict__ dst,
                                                    const int* __restrict__ HT,
                                                    int* __restrict__ pk) {
    __shared__ int cur[BUCKETS];
    int t = threadIdx.x;
    for (int i = t; i < BUCKETS; i += 256) cur[i] = HT[i * NBLK + blockIdx.x];
    __syncthreads();
    int base = blockIdx.x * EPB;
    for (int i = t; i < EPB; i += 256) {
        int d = dst[base + i];
        int s = src[base + i];
        int pos = atomicAdd(&cur[d >> 8], 1);
        pk[pos] = s | ((d & 255) << 24);    // src < 2^17, node-in-bucket in [24:32)
    }
}

__global__ __launch_bounds__(256) void sortD_kernel(const int* __restrict__ pk,
                                                    const int* __restrict__ HT,
                                                    int* __restrict__ ssrc,
                                                    int* __restrict__ cnt,
                                                    int* __restrict__ rowend) {
    __shared__ int h[256], sc_[256], cur[256];
    int b = blockIdx.x;
    int t = threadIdx.x;
    int start = HT[b * NBLK];
    int end = (b == BUCKETS - 1) ? N_EDGES : HT[(b + 1) * NBLK];
    h[t] = 0;
    __syncthreads();
    for (int i = start + t; i < end; i += 256) atomicAdd(&h[((unsigned)pk[i]) >> 24], 1);
    __syncthreads();
    int v = h[t];
    sc_[t] = v;
    __syncthreads();
    for (int d = 1; d < 256; d <<= 1) {
        int a = (t >= d) ? sc_[t - d] : 0;
        __syncthreads();
        sc_[t] += a;
        __syncthreads();
    }
    int excl = sc_[t] - v;
    int node = b * 256 + t;
    cnt[node] = v;
    rowend[node] = start + excl + v;
    cur[t] = start + excl;
    __syncthreads();
    for (int i = start + t; i < end; i += 256) {
        int p = pk[i];
        int pos = atomicAdd(&cur[((unsigned)p) >> 24], 1);
        ssrc[pos] = p & 0xFFFFFF;
    }
}

// --- conv1 gather: 4 neighbors/instr via quarter-wave, aligned 16B loads -----
// xb rows are padded [N][128] (pad = 0, sum-neutral); no tail masking needed.
// Ac1[n] = [ bf16(mean_{j in N(n)} xb[j]) (116) | xb[n] (116) | 0 (24) ]
__global__ __launch_bounds__(256) void gather1_kernel(
    const int* __restrict__ ssrc, const int* __restrict__ rowend,
    const int* __restrict__ cnt, const __hip_bfloat16* __restrict__ xb,
    __hip_bfloat16* __restrict__ Ac1) {
    int node = blockIdx.x * 4 + (threadIdx.x >> 6);
    int lane = threadIdx.x & 63;
    if (node >= N_NODES) return;
    int deg = cnt[node];
    int start = rowend[node] - deg;
    const int qw = lane >> 4;   // quarter: which of 4 in-flight neighbors
    const int l  = lane & 15;   // 16B chunk 0..15 (chunk 15 = pure pad)
    const unsigned short* xbs = (const unsigned short*)xb;
    float f0 = 0.f, f1 = 0.f, f2 = 0.f, f3 = 0.f;
    float f4 = 0.f, f5 = 0.f, f6 = 0.f, f7 = 0.f;

#define G1Q(J)                                                                  \
    {                                                                           \
        int jj = (J) + qw;                                                      \
        int s = __shfl(idx, jj);                                                \
        ulonglong2 u = {0ull, 0ull};                                            \
        if (jj < n)                                                             \
            u = *(const ulonglong2*)(xbs + (long)s * 128 + l * 8);              \
        unsigned a0 = (unsigned)u.x, a1 = (unsigned)(u.x >> 32);                \
        unsigned a2 = (unsigned)u.y, a3 = (unsigned)(u.y >> 32);                \
        f0 += bflo(a0); f1 += bfhi(a0); f2 += bflo(a1); f3 += bfhi(a1);         \
        f4 += bflo(a2); f5 += bfhi(a2); f6 += bflo(a3); f7 += bfhi(a3);         \
    }

    for (int base = 0; base < deg; base += 64) {
        int n = min(deg - base, 64);
        int idx = (lane < n) ? ssrc[start + base + lane] : 0;
        for (int j = 0; j < n; j += 16) {
            G1Q(j) G1Q(j + 4) G1Q(j + 8) G1Q(j + 12)
        }
    }
#undef G1Q
    f0 += __shfl_xor(f0, 16); f0 += __shfl_xor(f0, 32);
    f1 += __shfl_xor(f1, 16); f1 += __shfl_xor(f1, 32);
    f2 += __shfl_xor(f2, 16); f2 += __shfl_xor(f2, 32);
    f3 += __shfl_xor(f3, 16); f3 += __shfl_xor(f3, 32);
    f4 += __shfl_xor(f4, 16); f4 += __shfl_xor(f4, 32);
    f5 += __shfl_xor(f5, 16); f5 += __shfl_xor(f5, 32);
    f6 += __shfl_xor(f6, 16); f6 += __shfl_xor(f6, 32);
    f7 += __shfl_xor(f7, 16); f7 += __shfl_xor(f7, 32);

    unsigned short* rowp = (unsigned short*)Ac1 + (long)node * 256;
    if (lane < 15) {                 // mean chunks (feats 0..115)
        float inv = 1.f / fmaxf((float)deg, 1.f);
        __hip_bfloat162 p0, p1, p2, p3;
        p0.x = __float2bfloat16(f0 * inv); p0.y = __float2bfloat16(f1 * inv);
        p1.x = __float2bfloat16(f2 * inv); p1.y = __float2bfloat16(f3 * inv);
        p2.x = __float2bfloat16(f4 * inv); p2.y = __float2bfloat16(f5 * inv);
        p3.x = __float2bfloat16(f6 * inv); p3.y = __float2bfloat16(f7 * inv);
        unsigned u0 = *(unsigned*)&p0, u1 = *(unsigned*)&p1;
        unsigned u2 = *(unsigned*)&p2, u3 = *(unsigned*)&p3;
        unsigned long long w0 = (unsigned long long)u0 | ((unsigned long long)u1 << 32);
        unsigned long long w1 = (unsigned long long)u2 | ((unsigned long long)u3 << 32);
        if (lane < 14) {
            ulonglong2 o = {w0, w1};
            *(ulonglong2*)(rowp + lane * 8) = o;
        } else {
            *(unsigned long long*)(rowp + 112) = w0;   // feats 112..115
        }
    } else if (lane >= 16 && lane < 45) {   // self-row copy, 29 x 8B
        int sl = lane - 16;
        *(unsigned long long*)(rowp + NROI + 4 * sl) =
            *(const unsigned long long*)(xbs + (long)node * 128 + 4 * sl);
    } else if (lane >= 45 && lane < 51) {   // zero pad, 6 x 8B
        int zl = lane - 45;
        *(unsigned long long*)(rowp + 2 * NROI + 4 * zl) = 0ull;
    }
}

// --- conv2 gather: 4 neighbors/instr via quarter-wave, 8B loads --------------
__global__ __launch_bounds__(256) void gather2_kernel(
    const int* __restrict__ ssrc, const int* __restrict__ rowend,
    const int* __restrict__ cnt, const __hip_bfloat16* __restrict__ q,
    const float* __restrict__ b2, __hip_bfloat16* __restrict__ h2bf) {
    int node = blockIdx.x * 4 + (threadIdx.x >> 6);
    int lane = threadIdx.x & 63;
    if (node >= N_NODES) return;
    int deg = cnt[node];
    int start = rowend[node] - deg;
    const int qw = lane >> 4;
    const int l  = lane & 15;      // features 4l..4l+3
    const unsigned short* qs = (const unsigned short*)q;
    float g0 = 0.f, g1 = 0.f, g2 = 0.f, g3 = 0.f;

#define G2Q(J)                                                                  \
    {                                                                           \
        int jj = (J) + qw;                                                      \
        int s = __shfl(idx, jj);                                                \
        unsigned long long u = 0ull;                                            \
        if (jj < n) u = *(const unsigned long long*)(qs + (long)s * 128 + l * 4); \
        unsigned a0 = (unsigned)u, a1 = (unsigned)(u >> 32);                    \
        g0 += bflo(a0); g1 += bfhi(a0); g2 += bflo(a1); g3 += bfhi(a1);         \
    }

    for (int base = 0; base < deg; base += 64) {
        int n = min(deg - base, 64);
        int idx = (lane < n) ? ssrc[start + base + lane] : 0;
        for (int j = 0; j < n; j += 16) {
            G2Q(j) G2Q(j + 4) G2Q(j + 8) G2Q(j + 12)
        }
    }
#undef G2Q
    g0 += __shfl_xor(g0, 16); g0 += __shfl_xor(g0, 32);
    g1 += __shfl_xor(g1, 16); g1 += __shfl_xor(g1, 32);
    g2 += __shfl_xor(g2, 16); g2 += __shfl_xor(g2, 32);
    g3 += __shfl_xor(g3, 16); g3 += __shfl_xor(g3, 32);

    if (lane < 16) {
        float c = fmaxf((float)deg, 1.f);
        unsigned long long su = *(const unsigned long long*)(qs + (long)node * 128 + 64 + l * 4);
        unsigned s0 = (unsigned)su, s1 = (unsigned)(su >> 32);
        float4 bb = *(const float4*)(b2 + 4 * l);
        __hip_bfloat162 o0, o1;
        o0.x = __float2bfloat16(mishf(g0 / c + bflo(s0) + bb.x));
        o0.y = __float2bfloat16(mishf(g1 / c + bfhi(s0) + bb.y));
        o1.x = __float2bfloat16(mishf(g2 / c + bflo(s1) + bb.z));
        o1.y = __float2bfloat16(mishf(g3 / c + bfhi(s1) + bb.w));
        unsigned u0 = *(unsigned*)&o0, u1 = *(unsigned*)&o1;
        *(unsigned long long*)((unsigned short*)h2bf + (long)node * 64 + 4 * l) =
            (unsigned long long)u0 | ((unsigned long long)u1 << 32);
    }
}

// --- fused conv1+conv2 projection: q = (mish(Ac1 @ BT1^T + b1)) @ BT2^T ------
// m97-style staging: global_load_lds dwordx4 into LINEAR [128][32] LDS tiles.
// h1 tile [128][128] round-trips through LDS (C-layout -> A-layout), never HBM.
__global__ __launch_bounds__(256) void conv_fused_kernel(
    const __hip_bfloat16* __restrict__ Ac1,   // [N][256]
    const __hip_bfloat16* __restrict__ BT1,   // [128][256]
    const float* __restrict__ bias1p,         // [128]
    const __hip_bfloat16* __restrict__ BT2,   // [128][128]
    __hip_bfloat16* __restrict__ q) {         // [N][128]
    __shared__ __attribute__((aligned(16))) short As[128 * 32];
    __shared__ __attribute__((aligned(16))) short Bs[128 * 32];
    __shared__ short Ah[128][136];   // stride 136 shorts = 272B: 16B-aligned, 2-way banks
    const int t = threadIdx.x;
    const long row0 = (long)blockIdx.x * 128;
    const int w = t >> 6;

    // staging: thread t covers tile row (t>>2), 16B chunk (t&3); wave w's 64
    // lanes land linearly at As + w*512 elems (1024B) + lane*16B.
    const short* Ap = (const short*)Ac1 + (row0 + (t >> 2)) * 256 + ((t & 3) << 3);
    const short* Bp = (const short*)BT1 + (t >> 2) * 256 + ((t & 3) << 3);
    short* AsW = As + (w << 9);
    short* BsW = Bs + (w << 9);

    const int lane = t & 63;
    const int wid = w;
    const int wr = (wid >> 1) << 6;
    const int wc = (wid & 1) << 6;
    const int fm = lane & 15;
    const int fk = (lane >> 4) << 3;
    const int quad4 = (lane >> 4) << 2;

    f32x4 acc[4][4];
#pragma unroll
    for (int i = 0; i < 4; i++)
#pragma unroll
        for (int j = 0; j < 4; j++) acc[i][j] = (f32x4){0.f, 0.f, 0.f, 0.f};

    // phase 1: K=256 over BT1
    for (int k0 = 0; k0 < 256; k0 += 32) {
        gload16(Ap + k0, AsW);                       // rows 0..63
        gload16(Ap + 64 * 256 + k0, AsW + 2048);     // rows 64..127
        gload16(Bp + k0, BsW);
        gload16(Bp + 64 * 256 + k0, BsW + 2048);
        __syncthreads();                             // drains vmcnt(0)
        s16x8 a[4], b[4];
#pragma unroll
        for (int i = 0; i < 4; i++) a[i] = *(const s16x8*)&As[(wr + i * 16 + fm) * 32 + fk];
#pragma unroll
        for (int j = 0; j < 4; j++) b[j] = *(const s16x8*)&Bs[(wc + j * 16 + fm) * 32 + fk];
#pragma unroll
        for (int i = 0; i < 4; i++)
#pragma unroll
            for (int j = 0; j < 4; j++)
                acc[i][j] = __builtin_amdgcn_mfma_f32_16x16x32_bf16(
                    a[i], b[j], acc[i][j], 0, 0, 0);
        __syncthreads();
    }

    // mish(h1 + bias) -> Ah (LDS, A-operand layout source)
    __hip_bfloat16* Ahb = (__hip_bfloat16*)&Ah[0][0];
#pragma unroll
    for (int i = 0; i < 4; i++) {
#pragma unroll
        for (int j = 0; j < 4; j++) {
            int gc = wc + j * 16 + fm;
            float bv = bias1p[gc];
#pragma unroll
            for (int r = 0; r < 4; r++) {
                int lr = wr + i * 16 + quad4 + r;
                Ahb[lr * 136 + gc] = __float2bfloat16(mishf(acc[i][j][r] + bv));
            }
        }
    }
    __syncthreads();

    // phase 2: q = h1 @ BT2^T, K=128, BT2 staged via Bs (L2-hot)
    f32x4 acc2[4][4];
#pragma unroll
    for (int i = 0; i < 4; i++)
#pragma unroll
        for (int j = 0; j < 4; j++) acc2[i][j] = (f32x4){0.f, 0.f, 0.f, 0.f};

    const short* Bp2 = (const short*)BT2 + (t >> 2) * 128 + ((t & 3) << 3);
    for (int k0 = 0; k0 < 128; k0 += 32) {
        gload16(Bp2 + k0, BsW);
        gload16(Bp2 + 64 * 128 + k0, BsW + 2048);
        __syncthreads();
        s16x8 a[4], b[4];
#pragma unroll
        for (int i = 0; i < 4; i++) a[i] = *(const s16x8*)&Ah[wr + i * 16 + fm][k0 + fk];
#pragma unroll
        for (int j = 0; j < 4; j++) b[j] = *(const s16x8*)&Bs[(wc + j * 16 + fm) * 32 + fk];
#pragma unroll
        for (int i = 0; i < 4; i++)
#pragma unroll
            for (int j = 0; j < 4; j++)
                acc2[i][j] = __builtin_amdgcn_mfma_f32_16x16x32_bf16(
                    a[i], b[j], acc2[i][j], 0, 0, 0);
        __syncthreads();
    }

#pragma unroll
    for (int i = 0; i < 4; i++) {
#pragma unroll
        for (int j = 0; j < 4; j++) {
            int gc = wc + j * 16 + fm;
#pragma unroll
            for (int r = 0; r < 4; r++) {
                long gr = row0 + wr + i * 16 + quad4 + r;
                q[gr * 128 + gc] = __float2bfloat16(acc2[i][j][r]);
            }
        }
    }
}

// --- tiled transpose + fp32->bf16: W[7424][3712] -> WT[3712][7424] -----------
__global__ __launch_bounds__(256) void transpose_bf16_kernel(
    const float* __restrict__ W, __hip_bfloat16* __restrict__ WT) {
    __shared__ float tile[32][33];
    const int t = threadIdx.x;
    const int tn = t & 31, tk = t >> 5;
    const int n0 = blockIdx.x * 32;
    const int k0 = blockIdx.y * 32;
#pragma unroll
    for (int i = 0; i < 4; i++) {
        tile[tk + i * 8][tn] = W[(long)(k0 + tk + i * 8) * D1 + (n0 + tn)];
    }
    __syncthreads();
#pragma unroll
    for (int i = 0; i < 4; i++) {
        int n = n0 + tk + i * 8;
        int k = k0 + tn;
        WT[(long)n * KDIM + k] = __float2bfloat16(tile[tn][tk + i * 8]);
    }
}

// --- lin1: 128x128, BK=32, swizzled LDS, 2-buffer prefetch, split-K x4 -------
// Round-5 showed the 2-buf pipeline works but 64KB LDS capped residency at
// 2 blocks/CU (Occupancy 15%). BK=32 halves LDS to 32KB -> 4-5 blocks/CU,
// tripling the TLP that hides the DMA drain.
// 64B-pitch swizzle: XOR chunk with (row>>1)&3 (NOT row&3: row parity pins
// 8 lanes to one bank half; using bits[2:1] makes (parity,chunk) injective
// over 8 slots -> 2 lanes/slot = conflict-free).
// ks slowest in decode (A ks-panel L2-resident); NT C-writes.
__global__ __launch_bounds__(256) void lin1_mfma_kernel(
    const __hip_bfloat16* __restrict__ Abf,
    const __hip_bfloat16* __restrict__ BTbf,
    float* __restrict__ T) {
    __shared__ __attribute__((aligned(16))) short As[2][128 * 32];   // 2 x 8KB
    __shared__ __attribute__((aligned(16))) short Bs[2][128 * 32];   // 2 x 8KB
    const int t = threadIdx.x;
    const int id = blockIdx.x;
    const int xx = id & 7;
    const int k = id >> 3;
    const int r = k & 7;
    const int cg = (k >> 3) & 3;
    const int ks = k >> 5;
    const int c = xx + 8 * cg;
    if (c >= D1 / 128) return;     // 29 valid col stripes of 32
    const long row0 = (long)r * 128;
    const long col0 = (long)c * 128;
    const int kbase = ks * (KDIM / 4);       // 1856-chunk
    float* __restrict__ Cp = T + (long)ks * BATCH * D1;

    const int w = t >> 6;
    const int lane = t & 63;

    // staging: thread t covers tile row (t>>2) (0..63; +64 for second gload),
    // dest chunk (t&3). Source chunk inverse-swizzled by row bits[2:1]:
    // csrc = (t&3) ^ ((t>>3)&3)   [ (row>>1)&3 with row = t>>2 ].
    const int srow = t >> 2;                               // 0..63
    const int ksw = (((t & 3) ^ ((t >> 3) & 3)) << 3);     // element offset in row
    const short* ApS = (const short*)Abf + (row0 + srow) * KDIM + kbase + ksw;
    const short* BpS = (const short*)BTbf + (col0 + srow) * KDIM + kbase + ksw;
    const int wofs = w << 9;   // wave-uniform dest

    const int wr = (w >> 1) << 6;
    const int wc = (w & 1) << 6;
    const int fm = lane & 15;
    // swizzled read chunk (elements): q=lane>>4 XOR (row>>1)&3 = (fm>>1)&3
    const int ch0 = (((lane >> 4) ^ ((fm >> 1) & 3)) << 3);

    f32x4 acc[4][4];
#pragma unroll
    for (int i = 0; i < 4; i++)
#pragma unroll
        for (int j = 0; j < 4; j++) acc[i][j] = (f32x4){0.f, 0.f, 0.f, 0.f};

#define L1STAGE(bf, kk)                                            \
    {                                                              \
        gload16(ApS + (kk), &As[bf][wofs]);                        \
        gload16(ApS + 64 * KDIM + (kk), &As[bf][wofs + 2048]);     \
        gload16(BpS + (kk), &Bs[bf][wofs]);                        \
        gload16(BpS + 64 * KDIM + (kk), &Bs[bf][wofs + 2048]);     \
    }
#define L1COMP(bf)                                                              \
    {                                                                           \
        s16x8 a[4], b[4];                                                       \
        _Pragma("unroll")                                                       \
        for (int i = 0; i < 4; i++)                                             \
            a[i] = *(const s16x8*)&As[bf][(wr + i * 16 + fm) * 32 + ch0];       \
        _Pragma("unroll")                                                       \
        for (int j = 0; j < 4; j++)                                             \
            b[j] = *(const s16x8*)&Bs[bf][(wc + j * 16 + fm) * 32 + ch0];       \
        _Pragma("unroll")                                                       \
        for (int i = 0; i < 4; i++)                                             \
            _Pragma("unroll")                                                   \
            for (int j = 0; j < 4; j++)                                         \
                acc[i][j] = __builtin_amdgcn_mfma_f32_16x16x32_bf16(            \
                    a[i], b[j], acc[i][j], 0, 0, 0);                            \
    }

    const int NT = (KDIM / 4) / 32;   // 58 K-steps (even)
    L1STAGE(0, 0)
    __syncthreads();                  // buf0 ready
    for (int it = 0; it < NT; it += 2) {
        if (it + 1 < NT) L1STAGE(1, (it + 1) * 32)   // prefetch odd tile
        L1COMP(0)                                    // compute even tile
        __syncthreads();                             // drain AFTER compute
        if (it + 1 < NT) {
            if (it + 2 < NT) L1STAGE(0, (it + 2) * 32)
            L1COMP(1)
            __syncthreads();
        }
    }
#undef L1STAGE
#undef L1COMP

#pragma unroll
    for (int i = 0; i < 4; i++) {
#pragma unroll
        for (int j = 0; j < 4; j++) {
            int gc = (int)col0 + wc + j * 16 + fm;
#pragma unroll
            for (int r2 = 0; r2 < 4; r2++) {
                long gr = row0 + wr + i * 16 + ((lane >> 4) << 2) + r2;
                __builtin_nontemporal_store(acc[i][j][r2], &Cp[gr * D1 + gc]);
            }
        }
    }
}

// --- fused (sum 4 partials + bias) + layernorm + mish + lin2 tail ------------
// vc[] statically unrolled (compile-time indices -> registers, rule #20;
// the runtime-indexed version allocated vc in scratch).
__global__ __launch_bounds__(256) void tail_kernel(
    const float* __restrict__ T, const float* __restrict__ bias,
    const float* __restrict__ g, const float* __restrict__ b,
    const float* __restrict__ w2, const float* __restrict__ b2,
    float* __restrict__ out) {
    int row = blockIdx.x;
    const float* p0 = T + (long)row * D1;
    const float* p1 = p0 + (long)BATCH * D1;
    const float* p2 = p1 + (long)BATCH * D1;
    const float* p3 = p2 + (long)BATCH * D1;
    int t = threadIdx.x;
    int w = t >> 6, lane = t & 63;
    float vc[15];
    float s = 0.f, ss = 0.f;
#pragma unroll
    for (int u = 0; u < 15; u++) {
        int i = t + u * 256;
        float v = 0.f;
        if (i < D1) v = (p0[i] + p1[i]) + (p2[i] + p3[i]) + bias[i];
        vc[u] = v;
        s += v;
        ss += v * v;
    }
    for (int d = 32; d > 0; d >>= 1) {
        s += __shfl_down(s, d);
        ss += __shfl_down(ss, d);
    }
    __shared__ float sh[8];
    if (lane == 0) { sh[w] = s; sh[4 + w] = ss; }
    __syncthreads();
    if (t == 0) {
        sh[0] = sh[0] + sh[1] + sh[2] + sh[3];
        sh[4] = sh[4] + sh[5] + sh[6] + sh[7];
    }
    __syncthreads();
    float mu = sh[0] * (1.f / D1);
    float var = sh[4] * (1.f / D1) - mu * mu;
    float rs = rsqrtf(var + 1e-5f);
    float d0 = 0.f, d1 = 0.f;
#pragma unroll
    for (int u = 0; u < 15; u++) {
        int i = t + u * 256;
        if (i < D1) {
            float v = (vc[u] - mu) * rs * g[i] + b[i];
            v = mishf(v);
            d0 += v * w2[2 * i];
            d1 += v * w2[2 * i + 1];
        }
    }
    for (int d = 32; d > 0; d >>= 1) {
        d0 += __shfl_down(d0, d);
        d1 += __shfl_down(d1, d);
    }
    __shared__ float sh2[8];
    if (lane == 0) { sh2[w] = d0; sh2[4 + w] = d1; }
    __syncthreads();
    if (t == 0) {
        out[2 * row] = sh2[0] + sh2[1] + sh2[2] + sh2[3] + b2[0];
        out[2 * row + 1] = sh2[4] + sh2[5] + sh2[6] + sh2[7] + b2[1];
    }
}

extern "C" void kernel_launch(void* const* d_in, const int* in_sizes, int n_in,
                              void* d_out, int out_size, void* d_ws, size_t ws_size,
                              hipStream_t stream) {
    const float* x      = (const float*)d_in[0];
    const int*   ei     = (const int*)d_in[1];
    const float* w1_l   = (const float*)d_in[2];
    const float* b1     = (const float*)d_in[3];
    const float* w1_r   = (const float*)d_in[4];
    const float* w2_l   = (const float*)d_in[5];
    const float* b2     = (const float*)d_in[6];
    const float* w2_r   = (const float*)d_in[7];
    const float* w_lin1 = (const float*)d_in[8];
    const float* b_lin1 = (const float*)d_in[9];
    const float* ln_g   = (const float*)d_in[10];
    const float* ln_b   = (const float*)d_in[11];
    const float* w_lin2 = (const float*)d_in[12];
    const float* b_lin2 = (const float*)d_in[13];
    float* out = (float*)d_out;

    char* ws = (char*)d_ws;
    // workspace layout (bytes), liveness-based reuse (max ~161.1MB):
    //   [0,          60,817,408)  Ac1 bf16 [N][256] (gather1->conv_fused)
    //                             -> wT bf16 [3712][7424] (transpose->lin1)
    //   [60,817,408, 121,634,816) T fp32 [4][1024][3712] partials (lin1->tail)
    //     overlays: xb/q bf16 [N][128] at 91,226,112 (prep->gather1 /
    //     conv_fused->gather2, both dead before lin1 writes T; 30,408,704 B
    //     ends exactly at 121,634,816)
    //   [121,634,816,129,236,992) pk int[E] packed pairs (sortC->sortD)
    //   [136,839,168,137,314,304) cnt int[N]
    //   [137,314,304,137,789,440) rowend int[N]
    //   [137,789,440,138,220,032) HT int[464*232]
    //   [138,220,032,145,822,208) ssrc int[E]
    //   [145,822,208,161,026,560) h2bf bf16 [N][64] (gather2->lin1)
    //   [161,026,560,...)         BT1 ; bias1p ; BT2
    __hip_bfloat16* Ac1   = (__hip_bfloat16*)(ws + 0);
    __hip_bfloat16* wT    = (__hip_bfloat16*)(ws + 0);
    float* T              = (float*)(ws + 60817408);
    __hip_bfloat16* xb    = (__hip_bfloat16*)(ws + 91226112);
    __hip_bfloat16* q     = (__hip_bfloat16*)(ws + 91226112);
    int*   pk             = (int*)(ws + 121634816);
    int*   cnt            = (int*)(ws + 136839168);
    int*   rowend         = (int*)(ws + 137314304);
    int*   HT             = (int*)(ws + 137789440);
    int*   ssrc           = (int*)(ws + 138220032);
    __hip_bfloat16* h2bf  = (__hip_bfloat16*)(ws + 145822208);
    __hip_bfloat16* BT1   = (__hip_bfloat16*)(ws + 161026560);
    float* bias1p         = (float*)(ws + 161092096);
    __hip_bfloat16* BT2   = (__hip_bfloat16*)(ws + 161092608);

    const int* src = ei;
    const int* dst = ei + N_EDGES;

    // --- fused prep (BT1 + BT2 + xb padded [N][128]) ---
    prep_kernel<<<192 + (int)((long)N_NODES * 64 / 256), 256, 0, stream>>>(
        w1_l, w1_r, b1, w2_l, w2_r, x, BT1, bias1p, BT2, xb);

    // --- CSR build: deterministic 2-level counting sort (packed 4B pairs) ---
    sortA_kernel<<<NBLK, 256, 0, stream>>>(dst, HT);
    sortB_kernel<<<1, 1024, 0, stream>>>(HT);
    sortC_kernel<<<NBLK, 256, 0, stream>>>(src, dst, HT, pk);
    sortD_kernel<<<BUCKETS, 256, 0, stream>>>(pk, HT, ssrc, cnt, rowend);

    // --- conv1 gather-mean, then fused conv1-GEMM + conv2-projection ---
    gather1_kernel<<<(N_NODES + 3) / 4, 256, 0, stream>>>(ssrc, rowend, cnt, xb, Ac1);
    conv_fused_kernel<<<N_NODES / 128, 256, 0, stream>>>(Ac1, BT1, bias1p, BT2, q);

    // --- conv2 aggregation ---
    gather2_kernel<<<(N_NODES + 3) / 4, 256, 0, stream>>>(ssrc, rowend, cnt, q, b2, h2bf);

    // --- lin1 (128x128, BK=32 swizzled + 2-buffer, 32KB LDS, ks-slow decode,
    //     NT C-writes); wT overlays dead Ac1, T overlays dead q/xb region ---
    transpose_bf16_kernel<<<dim3(D1 / 32, KDIM / 32), 256, 0, stream>>>(w_lin1, wT);
    lin1_mfma_kernel<<<1024, 256, 0, stream>>>(h2bf, wT, T);

    // --- (sum partials + bias) + layernorm + mish + lin2 ---
    tail_kernel<<<BATCH, 256, 0, stream>>>(T, b_lin1, ln_g, ln_b, w_lin2, b_lin2, out);
}

// Round 8
// 560.117 us; speedup vs baseline: 1.0595x; 1.0595x over previous
//
#include <hip/hip_runtime.h>
#include <hip/hip_bf16.h>
#include <cstdint>

#define N_NODES 118784
#define N_EDGES 1900544
#define NROI 116
#define HID 64
#define D1 3712
#define BATCH 1024
#define KDIM 7424   // N_ROI * HIDDEN

// sort geometry: 232 blocks x 8192 edges == N_EDGES ; 464 buckets x 256 nodes == N_NODES
#define EPB 8192
#define NBLK 232
#define BUCKETS 464

typedef __attribute__((ext_vector_type(8))) short s16x8;
typedef __attribute__((ext_vector_type(4))) float f32x4;

__device__ __forceinline__ float mishf(float x) {
    if (x > 20.f) return x;
    float e = __expf(x);
    float n = e * e + 2.f * e;
    return x * n / (n + 2.f);
}
__device__ __forceinline__ float bflo(unsigned u) { return __uint_as_float(u << 16); }
__device__ __forceinline__ float bfhi(unsigned u) { return __uint_as_float(u & 0xFFFF0000u); }

// async global->LDS DMA, 16B per lane. LDS dest = wave-uniform base + lane*16.
__device__ __forceinline__ void gload16(const void* g, void* l) {
    __builtin_amdgcn_global_load_lds(
        (const __attribute__((address_space(1))) void*)g,
        (__attribute__((address_space(3))) void*)l, 16, 0, 0);
}

// --- fused prep: BT1/bias1p (blocks 0..127), BT2 (128..191), xb (192..) ------
// xb rows padded 116 -> 128 bf16 (256B): aligned 64B lines for gather1, pad=0.
__global__ __launch_bounds__(256) void prep_kernel(
    const float* __restrict__ w1_l, const float* __restrict__ w1_r,
    const float* __restrict__ b1,
    const float* __restrict__ w2_l, const float* __restrict__ w2_r,
    const float* __restrict__ x,
    __hip_bfloat16* __restrict__ BT1, float* __restrict__ bias1p,
    __hip_bfloat16* __restrict__ BT2, __hip_bfloat16* __restrict__ xb) {
    int bid = blockIdx.x, t = threadIdx.x;
    if (bid < 128) {            // BT1 [128][256] = padded [w1_l; w1_r]^T
        int idx = bid * 256 + t;
        int j = idx >> 8, k = idx & 255;
        float v = 0.f;
        if (j < NROI) {
            if (k < NROI) v = w1_l[k * NROI + j];
            else if (k < 2 * NROI) v = w1_r[(k - NROI) * NROI + j];
        }
        BT1[idx] = __float2bfloat16(v);
        if (idx < 128) bias1p[idx] = (idx < NROI) ? b1[idx] : 0.f;
    } else if (bid < 192) {     // BT2 [128][128] = padded [w2_l | w2_r]^T
        int idx = (bid - 128) * 256 + t;
        int j = idx >> 7, k = idx & 127;
        float v = 0.f;
        if (k < NROI) v = (j < HID) ? w2_l[k * HID + j] : w2_r[k * HID + (j - HID)];
        BT2[idx] = __float2bfloat16(v);
    } else {                    // xb: x fp32 -> bf16, padded [N][128] rows
        long i = (long)(bid - 192) * 256 + t;     // pair idx; grid gives i < N*64
        int node = (int)(i >> 6);
        int p = (int)(i & 63);                    // pair p covers cols 2p,2p+1
        __hip_bfloat162 o;
        if (p < 58) {
            float2 v = *(const float2*)(x + (long)node * NROI + 2 * p);
            o.x = __float2bfloat16(v.x);
            o.y = __float2bfloat16(v.y);
        } else {
            o.x = __float2bfloat16(0.f);
            o.y = __float2bfloat16(0.f);
        }
        *(__hip_bfloat162*)((__hip_bfloat16*)xb + 2 * i) = o;
    }
}

// =============== deterministic CSR build via 2-level counting sort ===========
__global__ __launch_bounds__(256) void sortA_kernel(const int* __restrict__ dst,
                                                    int* __restrict__ HT) {
    __shared__ int h[BUCKETS];
    int t = threadIdx.x;
    for (int i = t; i < BUCKETS; i += 256) h[i] = 0;
    __syncthreads();
    int base = blockIdx.x * EPB;
    for (int i = t; i < EPB; i += 256) atomicAdd(&h[dst[base + i] >> 8], 1);
    __syncthreads();
    for (int i = t; i < BUCKETS; i += 256) HT[i * NBLK + blockIdx.x] = h[i];
}

// prefix sum of 107648 ints, single block, wave-shuffle scan (4 barriers/chunk
// instead of 22 -- measured ~28us total saving with tail unroll, round 6).
__global__ __launch_bounds__(1024) void sortB_kernel(int* __restrict__ HT) {
    const int L = BUCKETS * NBLK;   // 107648
    __shared__ int wsum[16];
    __shared__ int carry_s;
    int t = threadIdx.x;
    int lane = t & 63, wv = t >> 6;
    if (t == 0) carry_s = 0;
    __syncthreads();
    for (int base = 0; base < L; base += 4096) {
        int i0 = base + 4 * t;
        int4 v = {0, 0, 0, 0};
        if (i0 + 3 < L) v = *(const int4*)(HT + i0);
        else {
            if (i0 < L) v.x = HT[i0];
            if (i0 + 1 < L) v.y = HT[i0 + 1];
            if (i0 + 2 < L) v.z = HT[i0 + 2];
        }
        int s4 = v.x + v.y + v.z + v.w;
        // wave-level inclusive scan of s4 (no barriers)
        int sc = s4;
#pragma unroll
        for (int d = 1; d < 64; d <<= 1) {
            int a = __shfl_up(sc, d);
            if (lane >= d) sc += a;
        }
        if (lane == 63) wsum[wv] = sc;
        __syncthreads();
        if (wv == 0 && lane < 16) {   // scan the 16 wave totals
            int xv = wsum[lane];
#pragma unroll
            for (int d = 1; d < 16; d <<= 1) {
                int a = __shfl_up(xv, d);
                if (lane >= d) xv += a;
            }
            wsum[lane] = xv;          // inclusive
        }
        __syncthreads();
        int wbase = (wv == 0) ? 0 : wsum[wv - 1];
        int carry = carry_s;
        int excl = carry + wbase + sc - s4;
        int4 o;
        o.x = excl; o.y = excl + v.x; o.z = o.y + v.y; o.w = o.z + v.z;
        if (i0 + 3 < L) *(int4*)(HT + i0) = o;
        else {
            if (i0 < L) HT[i0] = o.x;
            if (i0 + 1 < L) HT[i0 + 1] = o.y;
            if (i0 + 2 < L) HT[i0 + 2] = o.z;
        }
        __syncthreads();              // all reads of carry_s/wsum done
        if (t == 1023) carry_s = carry + wsum[15];
        __syncthreads();
    }
}

// C: scatter packed (src | dlow<<24) into bucket-sorted order (4B vs 8B pairs)
__global__ __launch_bounds__(256) void sortC_kernel(const int* __restrict__ src,
                                                    const int* __restrict__ dst,
                                                    const int* __restrict__ HT,
                                                    int* __restrict__ pk) {
    __shared__ int cur[BUCKETS];
    int t = threadIdx.x;
    for (int i = t; i < BUCKETS; i += 256) cur[i] = HT[i * NBLK + blockIdx.x];
    __syncthreads();
    int base = blockIdx.x * EPB;
    for (int i = t; i < EPB; i += 256) {
        int d = dst[base + i];
        int s = src[base + i];
        int pos = atomicAdd(&cur[d >> 8], 1);
        pk[pos] = s | ((d & 255) << 24);    // src < 2^17, node-in-bucket in [24:32)
    }
}

__global__ __launch_bounds__(256) void sortD_kernel(const int* __restrict__ pk,
                                                    const int* __restrict__ HT,
                                                    int* __restrict__ ssrc,
                                                    int* __restrict__ cnt,
                                                    int* __restrict__ rowend) {
    __shared__ int h[256], sc_[256], cur[256];
    int b = blockIdx.x;
    int t = threadIdx.x;
    int start = HT[b * NBLK];
    int end = (b == BUCKETS - 1) ? N_EDGES : HT[(b + 1) * NBLK];
    h[t] = 0;
    __syncthreads();
    for (int i = start + t; i < end; i += 256) atomicAdd(&h[((unsigned)pk[i]) >> 24], 1);
    __syncthreads();
    int v = h[t];
    sc_[t] = v;
    __syncthreads();
    for (int d = 1; d < 256; d <<= 1) {
        int a = (t >= d) ? sc_[t - d] : 0;
        __syncthreads();
        sc_[t] += a;
        __syncthreads();
    }
    int excl = sc_[t] - v;
    int node = b * 256 + t;
    cnt[node] = v;
    rowend[node] = start + excl + v;
    cur[t] = start + excl;
    __syncthreads();
    for (int i = start + t; i < end; i += 256) {
        int p = pk[i];
        int pos = atomicAdd(&cur[((unsigned)p) >> 24], 1);
        ssrc[pos] = p & 0xFFFFFF;
    }
}

// --- conv1 gather: 4 neighbors/instr via quarter-wave, aligned 16B loads -----
// xb rows are padded [N][128] (pad = 0, sum-neutral); no tail masking needed.
// Ac1[n] = [ bf16(mean_{j in N(n)} xb[j]) (116) | xb[n] (116) | 0 (24) ]
__global__ __launch_bounds__(256) void gather1_kernel(
    const int* __restrict__ ssrc, const int* __restrict__ rowend,
    const int* __restrict__ cnt, const __hip_bfloat16* __restrict__ xb,
    __hip_bfloat16* __restrict__ Ac1) {
    int node = blockIdx.x * 4 + (threadIdx.x >> 6);
    int lane = threadIdx.x & 63;
    if (node >= N_NODES) return;
    int deg = cnt[node];
    int start = rowend[node] - deg;
    const int qw = lane >> 4;   // quarter: which of 4 in-flight neighbors
    const int l  = lane & 15;   // 16B chunk 0..15 (chunk 15 = pure pad)
    const unsigned short* xbs = (const unsigned short*)xb;
    float f0 = 0.f, f1 = 0.f, f2 = 0.f, f3 = 0.f;
    float f4 = 0.f, f5 = 0.f, f6 = 0.f, f7 = 0.f;

#define G1Q(J)                                                                  \
    {                                                                           \
        int jj = (J) + qw;                                                      \
        int s = __shfl(idx, jj);                                                \
        ulonglong2 u = {0ull, 0ull};                                            \
        if (jj < n)                                                             \
            u = *(const ulonglong2*)(xbs + (long)s * 128 + l * 8);              \
        unsigned a0 = (unsigned)u.x, a1 = (unsigned)(u.x >> 32);                \
        unsigned a2 = (unsigned)u.y, a3 = (unsigned)(u.y >> 32);                \
        f0 += bflo(a0); f1 += bfhi(a0); f2 += bflo(a1); f3 += bfhi(a1);         \
        f4 += bflo(a2); f5 += bfhi(a2); f6 += bflo(a3); f7 += bfhi(a3);         \
    }

    for (int base = 0; base < deg; base += 64) {
        int n = min(deg - base, 64);
        int idx = (lane < n) ? ssrc[start + base + lane] : 0;
        for (int j = 0; j < n; j += 16) {
            G1Q(j) G1Q(j + 4) G1Q(j + 8) G1Q(j + 12)
        }
    }
#undef G1Q
    f0 += __shfl_xor(f0, 16); f0 += __shfl_xor(f0, 32);
    f1 += __shfl_xor(f1, 16); f1 += __shfl_xor(f1, 32);
    f2 += __shfl_xor(f2, 16); f2 += __shfl_xor(f2, 32);
    f3 += __shfl_xor(f3, 16); f3 += __shfl_xor(f3, 32);
    f4 += __shfl_xor(f4, 16); f4 += __shfl_xor(f4, 32);
    f5 += __shfl_xor(f5, 16); f5 += __shfl_xor(f5, 32);
    f6 += __shfl_xor(f6, 16); f6 += __shfl_xor(f6, 32);
    f7 += __shfl_xor(f7, 16); f7 += __shfl_xor(f7, 32);

    unsigned short* rowp = (unsigned short*)Ac1 + (long)node * 256;
    if (lane < 15) {                 // mean chunks (feats 0..115)
        float inv = 1.f / fmaxf((float)deg, 1.f);
        __hip_bfloat162 p0, p1, p2, p3;
        p0.x = __float2bfloat16(f0 * inv); p0.y = __float2bfloat16(f1 * inv);
        p1.x = __float2bfloat16(f2 * inv); p1.y = __float2bfloat16(f3 * inv);
        p2.x = __float2bfloat16(f4 * inv); p2.y = __float2bfloat16(f5 * inv);
        p3.x = __float2bfloat16(f6 * inv); p3.y = __float2bfloat16(f7 * inv);
        unsigned u0 = *(unsigned*)&p0, u1 = *(unsigned*)&p1;
        unsigned u2 = *(unsigned*)&p2, u3 = *(unsigned*)&p3;
        unsigned long long w0 = (unsigned long long)u0 | ((unsigned long long)u1 << 32);
        unsigned long long w1 = (unsigned long long)u2 | ((unsigned long long)u3 << 32);
        if (lane < 14) {
            ulonglong2 o = {w0, w1};
            *(ulonglong2*)(rowp + lane * 8) = o;
        } else {
            *(unsigned long long*)(rowp + 112) = w0;   // feats 112..115
        }
    } else if (lane >= 16 && lane < 45) {   // self-row copy, 29 x 8B
        int sl = lane - 16;
        *(unsigned long long*)(rowp + NROI + 4 * sl) =
            *(const unsigned long long*)(xbs + (long)node * 128 + 4 * sl);
    } else if (lane >= 45 && lane < 51) {   // zero pad, 6 x 8B
        int zl = lane - 45;
        *(unsigned long long*)(rowp + 2 * NROI + 4 * zl) = 0ull;
    }
}

// --- conv2 gather: 4 neighbors/instr via quarter-wave, 8B loads --------------
__global__ __launch_bounds__(256) void gather2_kernel(
    const int* __restrict__ ssrc, const int* __restrict__ rowend,
    const int* __restrict__ cnt, const __hip_bfloat16* __restrict__ q,
    const float* __restrict__ b2, __hip_bfloat16* __restrict__ h2bf) {
    int node = blockIdx.x * 4 + (threadIdx.x >> 6);
    int lane = threadIdx.x & 63;
    if (node >= N_NODES) return;
    int deg = cnt[node];
    int start = rowend[node] - deg;
    const int qw = lane >> 4;
    const int l  = lane & 15;      // features 4l..4l+3
    const unsigned short* qs = (const unsigned short*)q;
    float g0 = 0.f, g1 = 0.f, g2 = 0.f, g3 = 0.f;

#define G2Q(J)                                                                  \
    {                                                                           \
        int jj = (J) + qw;                                                      \
        int s = __shfl(idx, jj);                                                \
        unsigned long long u = 0ull;                                            \
        if (jj < n) u = *(const unsigned long long*)(qs + (long)s * 128 + l * 4); \
        unsigned a0 = (unsigned)u, a1 = (unsigned)(u >> 32);                    \
        g0 += bflo(a0); g1 += bfhi(a0); g2 += bflo(a1); g3 += bfhi(a1);         \
    }

    for (int base = 0; base < deg; base += 64) {
        int n = min(deg - base, 64);
        int idx = (lane < n) ? ssrc[start + base + lane] : 0;
        for (int j = 0; j < n; j += 16) {
            G2Q(j) G2Q(j + 4) G2Q(j + 8) G2Q(j + 12)
        }
    }
#undef G2Q
    g0 += __shfl_xor(g0, 16); g0 += __shfl_xor(g0, 32);
    g1 += __shfl_xor(g1, 16); g1 += __shfl_xor(g1, 32);
    g2 += __shfl_xor(g2, 16); g2 += __shfl_xor(g2, 32);
    g3 += __shfl_xor(g3, 16); g3 += __shfl_xor(g3, 32);

    if (lane < 16) {
        float c = fmaxf((float)deg, 1.f);
        unsigned long long su = *(const unsigned long long*)(qs + (long)node * 128 + 64 + l * 4);
        unsigned s0 = (unsigned)su, s1 = (unsigned)(su >> 32);
        float4 bb = *(const float4*)(b2 + 4 * l);
        __hip_bfloat162 o0, o1;
        o0.x = __float2bfloat16(mishf(g0 / c + bflo(s0) + bb.x));
        o0.y = __float2bfloat16(mishf(g1 / c + bfhi(s0) + bb.y));
        o1.x = __float2bfloat16(mishf(g2 / c + bflo(s1) + bb.z));
        o1.y = __float2bfloat16(mishf(g3 / c + bfhi(s1) + bb.w));
        unsigned u0 = *(unsigned*)&o0, u1 = *(unsigned*)&o1;
        *(unsigned long long*)((unsigned short*)h2bf + (long)node * 64 + 4 * l) =
            (unsigned long long)u0 | ((unsigned long long)u1 << 32);
    }
}

// --- fused conv1+conv2 projection: q = (mish(Ac1 @ BT1^T + b1)) @ BT2^T ------
// m97-style staging: global_load_lds dwordx4 into LINEAR [128][32] LDS tiles.
// h1 tile [128][128] round-trips through LDS (C-layout -> A-layout), never HBM.
__global__ __launch_bounds__(256) void conv_fused_kernel(
    const __hip_bfloat16* __restrict__ Ac1,   // [N][256]
    const __hip_bfloat16* __restrict__ BT1,   // [128][256]
    const float* __restrict__ bias1p,         // [128]
    const __hip_bfloat16* __restrict__ BT2,   // [128][128]
    __hip_bfloat16* __restrict__ q) {         // [N][128]
    __shared__ __attribute__((aligned(16))) short As[128 * 32];
    __shared__ __attribute__((aligned(16))) short Bs[128 * 32];
    __shared__ short Ah[128][136];   // stride 136 shorts = 272B: 16B-aligned, 2-way banks
    const int t = threadIdx.x;
    const long row0 = (long)blockIdx.x * 128;
    const int w = t >> 6;

    // staging: thread t covers tile row (t>>2), 16B chunk (t&3); wave w's 64
    // lanes land linearly at As + w*512 elems (1024B) + lane*16B.
    const short* Ap = (const short*)Ac1 + (row0 + (t >> 2)) * 256 + ((t & 3) << 3);
    const short* Bp = (const short*)BT1 + (t >> 2) * 256 + ((t & 3) << 3);
    short* AsW = As + (w << 9);
    short* BsW = Bs + (w << 9);

    const int lane = t & 63;
    const int wid = w;
    const int wr = (wid >> 1) << 6;
    const int wc = (wid & 1) << 6;
    const int fm = lane & 15;
    const int fk = (lane >> 4) << 3;
    const int quad4 = (lane >> 4) << 2;

    f32x4 acc[4][4];
#pragma unroll
    for (int i = 0; i < 4; i++)
#pragma unroll
        for (int j = 0; j < 4; j++) acc[i][j] = (f32x4){0.f, 0.f, 0.f, 0.f};

    // phase 1: K=256 over BT1
    for (int k0 = 0; k0 < 256; k0 += 32) {
        gload16(Ap + k0, AsW);                       // rows 0..63
        gload16(Ap + 64 * 256 + k0, AsW + 2048);     // rows 64..127
        gload16(Bp + k0, BsW);
        gload16(Bp + 64 * 256 + k0, BsW + 2048);
        __syncthreads();                             // drains vmcnt(0)
        s16x8 a[4], b[4];
#pragma unroll
        for (int i = 0; i < 4; i++) a[i] = *(const s16x8*)&As[(wr + i * 16 + fm) * 32 + fk];
#pragma unroll
        for (int j = 0; j < 4; j++) b[j] = *(const s16x8*)&Bs[(wc + j * 16 + fm) * 32 + fk];
#pragma unroll
        for (int i = 0; i < 4; i++)
#pragma unroll
            for (int j = 0; j < 4; j++)
                acc[i][j] = __builtin_amdgcn_mfma_f32_16x16x32_bf16(
                    a[i], b[j], acc[i][j], 0, 0, 0);
        __syncthreads();
    }

    // mish(h1 + bias) -> Ah (LDS, A-operand layout source)
    __hip_bfloat16* Ahb = (__hip_bfloat16*)&Ah[0][0];
#pragma unroll
    for (int i = 0; i < 4; i++) {
#pragma unroll
        for (int j = 0; j < 4; j++) {
            int gc = wc + j * 16 + fm;
            float bv = bias1p[gc];
#pragma unroll
            for (int r = 0; r < 4; r++) {
                int lr = wr + i * 16 + quad4 + r;
                Ahb[lr * 136 + gc] = __float2bfloat16(mishf(acc[i][j][r] + bv));
            }
        }
    }
    __syncthreads();

    // phase 2: q = h1 @ BT2^T, K=128, BT2 staged via Bs (L2-hot)
    f32x4 acc2[4][4];
#pragma unroll
    for (int i = 0; i < 4; i++)
#pragma unroll
        for (int j = 0; j < 4; j++) acc2[i][j] = (f32x4){0.f, 0.f, 0.f, 0.f};

    const short* Bp2 = (const short*)BT2 + (t >> 2) * 128 + ((t & 3) << 3);
    for (int k0 = 0; k0 < 128; k0 += 32) {
        gload16(Bp2 + k0, BsW);
        gload16(Bp2 + 64 * 128 + k0, BsW + 2048);
        __syncthreads();
        s16x8 a[4], b[4];
#pragma unroll
        for (int i = 0; i < 4; i++) a[i] = *(const s16x8*)&Ah[wr + i * 16 + fm][k0 + fk];
#pragma unroll
        for (int j = 0; j < 4; j++) b[j] = *(const s16x8*)&Bs[(wc + j * 16 + fm) * 32 + fk];
#pragma unroll
        for (int i = 0; i < 4; i++)
#pragma unroll
            for (int j = 0; j < 4; j++)
                acc2[i][j] = __builtin_amdgcn_mfma_f32_16x16x32_bf16(
                    a[i], b[j], acc2[i][j], 0, 0, 0);
        __syncthreads();
    }

#pragma unroll
    for (int i = 0; i < 4; i++) {
#pragma unroll
        for (int j = 0; j < 4; j++) {
            int gc = wc + j * 16 + fm;
#pragma unroll
            for (int r = 0; r < 4; r++) {
                long gr = row0 + wr + i * 16 + quad4 + r;
                q[gr * 128 + gc] = __float2bfloat16(acc2[i][j][r]);
            }
        }
    }
}

// --- tiled transpose + fp32->bf16: W[7424][3712] -> WT[3712][7424] -----------
__global__ __launch_bounds__(256) void transpose_bf16_kernel(
    const float* __restrict__ W, __hip_bfloat16* __restrict__ WT) {
    __shared__ float tile[32][33];
    const int t = threadIdx.x;
    const int tn = t & 31, tk = t >> 5;
    const int n0 = blockIdx.x * 32;
    const int k0 = blockIdx.y * 32;
#pragma unroll
    for (int i = 0; i < 4; i++) {
        tile[tk + i * 8][tn] = W[(long)(k0 + tk + i * 8) * D1 + (n0 + tn)];
    }
    __syncthreads();
#pragma unroll
    for (int i = 0; i < 4; i++) {
        int n = n0 + tk + i * 8;
        int k = k0 + tn;
        WT[(long)n * KDIM + k] = __float2bfloat16(tile[tn][tk + i * 8]);
    }
}

// --- lin1: 128x128, BK=64, XOR-swizzled LDS, 2-buffer prefetch, split-K x4 ---
// Round-5 measured best (81us): conflict-free swizzled reads + 2-buf pipeline.
// Round-6's BK=32 regressed (barrier overhead doubled, occupancy gain small) --
// reverted. ks slowest in decode (A ks-panel L2-resident); NT C-writes.
__global__ __launch_bounds__(256) void lin1_mfma_kernel(
    const __hip_bfloat16* __restrict__ Abf,
    const __hip_bfloat16* __restrict__ BTbf,
    float* __restrict__ T) {
    __shared__ __attribute__((aligned(16))) short As[2][128 * 64];   // 2 x 16KB
    __shared__ __attribute__((aligned(16))) short Bs[2][128 * 64];   // 2 x 16KB
    const int t = threadIdx.x;
    const int id = blockIdx.x;
    const int xx = id & 7;
    const int k = id >> 3;
    const int r = k & 7;
    const int cg = (k >> 3) & 3;
    const int ks = k >> 5;
    const int c = xx + 8 * cg;
    if (c >= D1 / 128) return;     // 29 valid col stripes of 32
    const long row0 = (long)r * 128;
    const long col0 = (long)c * 128;
    const int kbase = ks * (KDIM / 4);       // 1856-chunk
    float* __restrict__ Cp = T + (long)ks * BATCH * D1;

    const int w = t >> 6;
    const int lane = t & 63;

    // staging: thread t covers tile row (t>>3) within each 32-row group, and
    // destination 16B chunk (t&7). Source chunk is inverse-swizzled:
    // csrc = (t&7) ^ (row&7), row&7 = (t>>3)&7.
    const int srow = t >> 3;                               // 0..31
    const int ksw = (((t & 7) ^ ((t >> 3) & 7)) << 3);     // element offset in row
    const short* ApS = (const short*)Abf + (row0 + srow) * KDIM + kbase + ksw;
    const short* BpS = (const short*)BTbf + (col0 + srow) * KDIM + kbase + ksw;
    const int wofs = w << 9;   // wave-uniform dest; +2048 elems per 32-row group

    const int wr = (w >> 1) << 6;
    const int wc = (w & 1) << 6;
    const int fm = lane & 15;
    // swizzled read chunk offsets (elements): ksub0 chunk = (lane>>4)^(fm&7),
    // ksub1 = same ^ 4  ->  element offset ^ 32.
    const int ch0 = (((lane >> 4) ^ (fm & 7)) << 3);
    const int ch1 = ch0 ^ 32;

    f32x4 acc[4][4];
#pragma unroll
    for (int i = 0; i < 4; i++)
#pragma unroll
        for (int j = 0; j < 4; j++) acc[i][j] = (f32x4){0.f, 0.f, 0.f, 0.f};

#define L1STAGE(bf, kk)                                            \
    {                                                              \
        gload16(ApS + (kk), &As[bf][wofs]);                        \
        gload16(ApS + 32 * KDIM + (kk), &As[bf][wofs + 2048]);     \
        gload16(ApS + 64 * KDIM + (kk), &As[bf][wofs + 4096]);     \
        gload16(ApS + 96 * KDIM + (kk), &As[bf][wofs + 6144]);     \
        gload16(BpS + (kk), &Bs[bf][wofs]);                        \
        gload16(BpS + 32 * KDIM + (kk), &Bs[bf][wofs + 2048]);     \
        gload16(BpS + 64 * KDIM + (kk), &Bs[bf][wofs + 4096]);     \
        gload16(BpS + 96 * KDIM + (kk), &Bs[bf][wofs + 6144]);     \
    }
#define L1COMP(bf)                                                              \
    {                                                                           \
        s16x8 a[4], b[4];                                                       \
        _Pragma("unroll")                                                       \
        for (int i = 0; i < 4; i++)                                             \
            a[i] = *(const s16x8*)&As[bf][(wr + i * 16 + fm) * 64 + ch0];       \
        _Pragma("unroll")                                                       \
        for (int j = 0; j < 4; j++)                                             \
            b[j] = *(const s16x8*)&Bs[bf][(wc + j * 16 + fm) * 64 + ch0];       \
        _Pragma("unroll")                                                       \
        for (int i = 0; i < 4; i++)                                             \
            _Pragma("unroll")                                                   \
            for (int j = 0; j < 4; j++)                                         \
                acc[i][j] = __builtin_amdgcn_mfma_f32_16x16x32_bf16(            \
                    a[i], b[j], acc[i][j], 0, 0, 0);                            \
        _Pragma("unroll")                                                       \
        for (int i = 0; i < 4; i++)                                             \
            a[i] = *(const s16x8*)&As[bf][(wr + i * 16 + fm) * 64 + ch1];       \
        _Pragma("unroll")                                                       \
        for (int j = 0; j < 4; j++)                                             \
            b[j] = *(const s16x8*)&Bs[bf][(wc + j * 16 + fm) * 64 + ch1];       \
        _Pragma("unroll")                                                       \
        for (int i = 0; i < 4; i++)                                             \
            _Pragma("unroll")                                                   \
            for (int j = 0; j < 4; j++)                                         \
                acc[i][j] = __builtin_amdgcn_mfma_f32_16x16x32_bf16(            \
                    a[i], b[j], acc[i][j], 0, 0, 0);                            \
    }

    const int NT = (KDIM / 4) / 64;   // 29 K-tiles of 64
    L1STAGE(0, 0)
    __syncthreads();                  // buf0 ready
    for (int it = 0; it < NT; it += 2) {
        if (it + 1 < NT) L1STAGE(1, (it + 1) * 64)   // prefetch odd tile
        L1COMP(0)                                    // compute even tile
        __syncthreads();                             // drain AFTER compute
        if (it + 1 < NT) {
            if (it + 2 < NT) L1STAGE(0, (it + 2) * 64)
            L1COMP(1)
            __syncthreads();
        }
    }
#undef L1STAGE
#undef L1COMP

#pragma unroll
    for (int i = 0; i < 4; i++) {
#pragma unroll
        for (int j = 0; j < 4; j++) {
            int gc = (int)col0 + wc + j * 16 + fm;
#pragma unroll
            for (int r2 = 0; r2 < 4; r2++) {
                long gr = row0 + wr + i * 16 + ((lane >> 4) << 2) + r2;
                __builtin_nontemporal_store(acc[i][j][r2], &Cp[gr * D1 + gc]);
            }
        }
    }
}

// --- fused (sum 4 partials + bias) + layernorm + mish + lin2 tail ------------
// vc[] statically unrolled (compile-time indices -> registers, rule #20).
__global__ __launch_bounds__(256) void tail_kernel(
    const float* __restrict__ T, const float* __restrict__ bias,
    const float* __restrict__ g, const float* __restrict__ b,
    const float* __restrict__ w2, const float* __restrict__ b2,
    float* __restrict__ out) {
    int row = blockIdx.x;
    const float* p0 = T + (long)row * D1;
    const float* p1 = p0 + (long)BATCH * D1;
    const float* p2 = p1 + (long)BATCH * D1;
    const float* p3 = p2 + (long)BATCH * D1;
    int t = threadIdx.x;
    int w = t >> 6, lane = t & 63;
    float vc[15];
    float s = 0.f, ss = 0.f;
#pragma unroll
    for (int u = 0; u < 15; u++) {
        int i = t + u * 256;
        float v = 0.f;
        if (i < D1) v = (p0[i] + p1[i]) + (p2[i] + p3[i]) + bias[i];
        vc[u] = v;
        s += v;
        ss += v * v;
    }
    for (int d = 32; d > 0; d >>= 1) {
        s += __shfl_down(s, d);
        ss += __shfl_down(ss, d);
    }
    __shared__ float sh[8];
    if (lane == 0) { sh[w] = s; sh[4 + w] = ss; }
    __syncthreads();
    if (t == 0) {
        sh[0] = sh[0] + sh[1] + sh[2] + sh[3];
        sh[4] = sh[4] + sh[5] + sh[6] + sh[7];
    }
    __syncthreads();
    float mu = sh[0] * (1.f / D1);
    float var = sh[4] * (1.f / D1) - mu * mu;
    float rs = rsqrtf(var + 1e-5f);
    float d0 = 0.f, d1 = 0.f;
#pragma unroll
    for (int u = 0; u < 15; u++) {
        int i = t + u * 256;
        if (i < D1) {
            float v = (vc[u] - mu) * rs * g[i] + b[i];
            v = mishf(v);
            d0 += v * w2[2 * i];
            d1 += v * w2[2 * i + 1];
        }
    }
    for (int d = 32; d > 0; d >>= 1) {
        d0 += __shfl_down(d0, d);
        d1 += __shfl_down(d1, d);
    }
    __shared__ float sh2[8];
    if (lane == 0) { sh2[w] = d0; sh2[4 + w] = d1; }
    __syncthreads();
    if (t == 0) {
        out[2 * row] = sh2[0] + sh2[1] + sh2[2] + sh2[3] + b2[0];
        out[2 * row + 1] = sh2[4] + sh2[5] + sh2[6] + sh2[7] + b2[1];
    }
}

extern "C" void kernel_launch(void* const* d_in, const int* in_sizes, int n_in,
                              void* d_out, int out_size, void* d_ws, size_t ws_size,
                              hipStream_t stream) {
    const float* x      = (const float*)d_in[0];
    const int*   ei     = (const int*)d_in[1];
    const float* w1_l   = (const float*)d_in[2];
    const float* b1     = (const float*)d_in[3];
    const float* w1_r   = (const float*)d_in[4];
    const float* w2_l   = (const float*)d_in[5];
    const float* b2     = (const float*)d_in[6];
    const float* w2_r   = (const float*)d_in[7];
    const float* w_lin1 = (const float*)d_in[8];
    const float* b_lin1 = (const float*)d_in[9];
    const float* ln_g   = (const float*)d_in[10];
    const float* ln_b   = (const float*)d_in[11];
    const float* w_lin2 = (const float*)d_in[12];
    const float* b_lin2 = (const float*)d_in[13];
    float* out = (float*)d_out;

    char* ws = (char*)d_ws;
    // workspace layout (bytes), liveness-based reuse (max ~161.1MB):
    //   [0,          60,817,408)  Ac1 bf16 [N][256] (gather1->conv_fused)
    //                             -> wT bf16 [3712][7424] (transpose->lin1)
    //   [60,817,408, 121,634,816) T fp32 [4][1024][3712] partials (lin1->tail)
    //     overlays: xb/q bf16 [N][128] at 91,226,112 (prep->gather1 /
    //     conv_fused->gather2, both dead before lin1 writes T; 30,408,704 B
    //     ends exactly at 121,634,816)
    //   [121,634,816,129,236,992) pk int[E] packed pairs (sortC->sortD)
    //   [136,839,168,137,314,304) cnt int[N]
    //   [137,314,304,137,789,440) rowend int[N]
    //   [137,789,440,138,220,032) HT int[464*232]
    //   [138,220,032,145,822,208) ssrc int[E]
    //   [145,822,208,161,026,560) h2bf bf16 [N][64] (gather2->lin1)
    //   [161,026,560,...)         BT1 ; bias1p ; BT2
    __hip_bfloat16* Ac1   = (__hip_bfloat16*)(ws + 0);
    __hip_bfloat16* wT    = (__hip_bfloat16*)(ws + 0);
    float* T              = (float*)(ws + 60817408);
    __hip_bfloat16* xb    = (__hip_bfloat16*)(ws + 91226112);
    __hip_bfloat16* q     = (__hip_bfloat16*)(ws + 91226112);
    int*   pk             = (int*)(ws + 121634816);
    int*   cnt            = (int*)(ws + 136839168);
    int*   rowend         = (int*)(ws + 137314304);
    int*   HT             = (int*)(ws + 137789440);
    int*   ssrc           = (int*)(ws + 138220032);
    __hip_bfloat16* h2bf  = (__hip_bfloat16*)(ws + 145822208);
    __hip_bfloat16* BT1   = (__hip_bfloat16*)(ws + 161026560);
    float* bias1p         = (float*)(ws + 161092096);
    __hip_bfloat16* BT2   = (__hip_bfloat16*)(ws + 161092608);

    const int* src = ei;
    const int* dst = ei + N_EDGES;

    // --- fused prep (BT1 + BT2 + xb padded [N][128]) ---
    prep_kernel<<<192 + (int)((long)N_NODES * 64 / 256), 256, 0, stream>>>(
        w1_l, w1_r, b1, w2_l, w2_r, x, BT1, bias1p, BT2, xb);

    // --- CSR build: deterministic 2-level counting sort (packed 4B pairs) ---
    sortA_kernel<<<NBLK, 256, 0, stream>>>(dst, HT);
    sortB_kernel<<<1, 1024, 0, stream>>>(HT);
    sortC_kernel<<<NBLK, 256, 0, stream>>>(src, dst, HT, pk);
    sortD_kernel<<<BUCKETS, 256, 0, stream>>>(pk, HT, ssrc, cnt, rowend);

    // --- conv1 gather-mean, then fused conv1-GEMM + conv2-projection ---
    gather1_kernel<<<(N_NODES + 3) / 4, 256, 0, stream>>>(ssrc, rowend, cnt, xb, Ac1);
    conv_fused_kernel<<<N_NODES / 128, 256, 0, stream>>>(Ac1, BT1, bias1p, BT2, q);

    // --- conv2 aggregation ---
    gather2_kernel<<<(N_NODES + 3) / 4, 256, 0, stream>>>(ssrc, rowend, cnt, q, b2, h2bf);

    // --- lin1 (128x128, BK=64 swizzled + 2-buffer [round-5 best], ks-slow
    //     decode, NT C-writes); wT overlays dead Ac1, T overlays dead q/xb ---
    transpose_bf16_kernel<<<dim3(D1 / 32, KDIM / 32), 256, 0, stream>>>(w_lin1, wT);
    lin1_mfma_kernel<<<1024, 256, 0, stream>>>(h2bf, wT, T);

    // --- (sum partials + bias) + layernorm + mish + lin2 ---
    tail_kernel<<<BATCH, 256, 0, stream>>>(T, b_lin1, ln_g, ln_b, w_lin2, b_lin2, out);
}